// Round 4
// baseline (338.116 us; speedup 1.0000x reference)
//
#include <hip/hip_runtime.h>
#include <hip/hip_cooperative_groups.h>
#include <math.h>

namespace cg = cooperative_groups;

// CLUB_NCE fused cooperative kernel: N=512, D=400, H=400.
// grid 256 x 1024 (1 block/CU, 16 waves/CU = 4 waves/SIMD).
// Phase 1: hidden GEMM -> hxT0/1 [h][n], hyb0/1 [n][h] (k-half partials, b1 in hyb0)
// Phase 2: pair scores s(i,j)=sum_h W2[h]*relu(hyb+hxT)+b2, fused softplus + fp64 reduce
// Phase 3: block 0: fp64 logsumexp -> (lower, upper)

#define NSAMP 512
#define DIM 400
#define HID 400

__global__ __launch_bounds__(1024, 4) void club_fused(
    const float* __restrict__ X, const float* __restrict__ Y,
    const float* __restrict__ W1, const float* __restrict__ b1,
    const float* __restrict__ W2, const float* __restrict__ b2,
    float* __restrict__ hxT0, float* __restrict__ hxT1,
    float* __restrict__ hyb0, float* __restrict__ hyb1,
    double* __restrict__ expsum, double* __restrict__ tsum,
    double* __restrict__ diagT, float* __restrict__ out)
{
    __shared__ __align__(16) float W2s[400];
    __shared__ __align__(16) float U[13200];   // 52.8 KB union (phase1/2/3)
    cg::grid_group grid = cg::this_grid();

    const int t   = threadIdx.x;
    const int blk = blockIdx.x;
    if (t < 400) W2s[t] = W2[t];

    // ---------------- Phase 1: hidden GEMM ----------------
    // job = 224: mat(2) x kh(2) x [n8(8) x h7(7)]. Tile 64n x 64h x 200k.
    if (blk < 224) {
        const int mat = blk & 1, kh = (blk >> 1) & 1, rem = blk >> 2;  // 0..55
        const int h7 = rem % 7, n8 = rem / 7;
        const float* __restrict__ src = mat ? Y : X;
        const int n0 = n8 * 64, h0 = h7 * 64;
        const int scol = kh * 200;
        const int wcol = (mat ? DIM : 0) + kh * 200;
        const int lo = t & 31, hi = t >> 5;
        const int n2 = mat ? hi : lo;   // n-pair index
        const int h2 = mat ? lo : hi;   // h-pair index

        float* As = U;          // [k][n] stride 66, 100 rows
        float* Bs = U + 6600;   // [k][h] stride 66

        float a00 = 0.f, a01 = 0.f, a10 = 0.f, a11 = 0.f;  // [n r][h c]

        for (int kc = 0; kc < 200; kc += 100) {
            __syncthreads();
            for (int idx = t; idx < 1600; idx += 1024) {
                int n = idx / 25, q = idx - n * 25;
                float4 v = *(const float4*)(src + (size_t)(n0 + n) * DIM + scol + kc + 4 * q);
                int base = 4 * q * 66 + n;
                As[base] = v.x; As[base + 66] = v.y; As[base + 132] = v.z; As[base + 198] = v.w;
            }
            for (int idx = t; idx < 1600; idx += 1024) {
                int h = idx / 25, q = idx - h * 25;
                int hr = h0 + h; if (hr > HID - 1) hr = HID - 1;
                float4 v = *(const float4*)(W1 + (size_t)hr * (2 * DIM) + wcol + kc + 4 * q);
                int base = 4 * q * 66 + h;
                Bs[base] = v.x; Bs[base + 66] = v.y; Bs[base + 132] = v.z; Bs[base + 198] = v.w;
            }
            __syncthreads();
#pragma unroll 4
            for (int k = 0; k < 100; k++) {
                float2 av = *(const float2*)(As + k * 66 + 2 * n2);
                float2 bv = *(const float2*)(Bs + k * 66 + 2 * h2);
                a00 = fmaf(av.x, bv.x, a00);
                a01 = fmaf(av.x, bv.y, a01);
                a10 = fmaf(av.y, bv.x, a10);
                a11 = fmaf(av.y, bv.y, a11);
            }
        }

        if (mat == 0) {   // n-pair = lo -> coalesced float2 along n in hxT[h][n]
            float* __restrict__ dst = kh ? hxT1 : hxT0;
            const int n = n0 + 2 * lo, h = h0 + 2 * hi;
            if (h < HID)     *(float2*)(dst + (size_t)h * NSAMP + n)       = make_float2(a00, a10);
            if (h + 1 < HID) *(float2*)(dst + (size_t)(h + 1) * NSAMP + n) = make_float2(a01, a11);
        } else {          // h-pair = lo -> coalesced float2 along h in hyb[n][h]
            float* __restrict__ dst = kh ? hyb1 : hyb0;
            const int h = h0 + 2 * lo, n = n0 + 2 * hi;
            if (h < HID) {
                float2 v0 = make_float2(a00, a01);
                float2 v1 = make_float2(a10, a11);
                if (kh == 0) {
                    float2 bv = *(const float2*)(b1 + h);
                    v0.x += bv.x; v0.y += bv.y; v1.x += bv.x; v1.y += bv.y;
                }
                *(float2*)(dst + (size_t)n * HID + h)       = v0;
                *(float2*)(dst + (size_t)(n + 1) * HID + h) = v1;
            }
        }
    }

    __threadfence();
    grid.sync();

    // ---------------- Phase 2: pair scores ----------------
    // 512 jobs = i-tile(32, 16 rows) x j-tile(16, 32 cols); 2 jobs/block (one per half).
    {
        const int half = t >> 9;
        const int tt   = t & 511;
        const int job  = blk * 2 + half;
        const int it = job >> 4, jt = job & 15;
        const int i0 = it * 16, j0 = jt * 32;
        const int tx = tt & 31;          // j
        const int ty = tt >> 5;          // i 0..15
        float* Ah = U + half * 5184;            // As[i][hl] 16 x 108
        float* Bh = U + half * 5184 + 16 * 108; // Bs[j][hl] 32 x 108 (transposed)

        float acc = 0.f;
        for (int hc = 0; hc < HID; hc += 100) {
            __syncthreads();
            // As[i][hl] = hyb0 + hyb1
            for (int idx = tt; idx < 400; idx += 512) {
                int i = idx / 25, q = idx - i * 25;
                size_t off = (size_t)(i0 + i) * HID + hc + 4 * q;
                float4 v0 = *(const float4*)(hyb0 + off);
                float4 v1 = *(const float4*)(hyb1 + off);
                *(float4*)(Ah + i * 108 + 4 * q) =
                    make_float4(v0.x + v1.x, v0.y + v1.y, v0.z + v1.z, v0.w + v1.w);
            }
            // Bs[j][hl] = hxT0 + hxT1 (transposed store)
            for (int idx = tt; idx < 800; idx += 512) {
                int h = idx >> 3, jq = idx & 7;
                size_t off = (size_t)(hc + h) * NSAMP + j0 + 4 * jq;
                float4 v0 = *(const float4*)(hxT0 + off);
                float4 v1 = *(const float4*)(hxT1 + off);
                float* d = Bh + (4 * jq) * 108 + h;
                d[0]   = v0.x + v1.x;
                d[108] = v0.y + v1.y;
                d[216] = v0.z + v1.z;
                d[324] = v0.w + v1.w;
            }
            __syncthreads();
            const float* ap = Ah + ty * 108;
            const float* bp = Bh + tx * 108;
            const float* wp = W2s + hc;
#pragma unroll 5
            for (int g = 0; g < 25; g++) {
                float4 av = *(const float4*)(ap + 4 * g);   // broadcast b128
                float4 bv = *(const float4*)(bp + 4 * g);   // conflict-free b128
                float4 wv = *(const float4*)(wp + 4 * g);   // broadcast b128
                acc = fmaf(fmaxf(av.x + bv.x, 0.f), wv.x, acc);
                acc = fmaf(fmaxf(av.y + bv.y, 0.f), wv.y, acc);
                acc = fmaf(fmaxf(av.z + bv.z, 0.f), wv.z, acc);
                acc = fmaf(fmaxf(av.w + bv.w, 0.f), wv.w, acc);
            }
        }

        // epilogue: softplus + fp64 reduce over the 32 j-lanes (aligned half-wave)
        const int i = i0 + ty, j = j0 + tx;
        float s  = acc + b2[0];
        float es = expf(s);
        float T  = log1pf(es);
        if (i == j) diagT[i] = (double)T;
        double eD = 1.0 + (double)es;   // exp(softplus(s)) exactly
        double tD = (double)T;
        for (int off = 16; off > 0; off >>= 1) {
            eD += __shfl_down(eD, off);
            tD += __shfl_down(tD, off);
        }
        if (tx == 0) {
            expsum[i * 16 + jt] = eD;
            tsum  [i * 16 + jt] = tD;
        }
    }

    __threadfence();
    grid.sync();

    // ---------------- Phase 3: final assembly (block 0) ----------------
    if (blk == 0) {
        double* sh = (double*)U;   // 3*512 doubles = 12 KB
        double lse = 0.0, tsm = 0.0, dg = 0.0;
        if (t < 512) {
            double es = 0.0, ts = 0.0;
#pragma unroll
            for (int b = 0; b < 16; b++) { es += expsum[t * 16 + b]; ts += tsum[t * 16 + b]; }
            lse = log(es); tsm = ts; dg = diagT[t];
        }
        __syncthreads();
        if (t < 512) { sh[t] = lse; sh[512 + t] = tsm; sh[1024 + t] = dg; }
        __syncthreads();
        for (int off = 256; off > 0; off >>= 1) {
            if (t < off) {
                sh[t]        += sh[t + off];
                sh[512 + t]  += sh[512 + t + off];
                sh[1024 + t] += sh[1024 + t + off];
            }
            __syncthreads();
        }
        if (t == 0) {
            double t0m  = sh[1024] / 512.0;
            double lsem = sh[0]    / 512.0;
            double t1m  = sh[512]  / (512.0 * 512.0);
            out[0] = (float)(t0m - (lsem - log(512.0)));
            out[1] = (float)(t0m - t1m);
        }
    }
}

extern "C" void kernel_launch(void* const* d_in, const int* in_sizes, int n_in,
                              void* d_out, int out_size, void* d_ws, size_t ws_size,
                              hipStream_t stream) {
    const float* X  = (const float*)d_in[0];
    const float* Y  = (const float*)d_in[1];
    const float* W1 = (const float*)d_in[2];
    const float* b1 = (const float*)d_in[3];
    const float* W2 = (const float*)d_in[4];
    const float* b2 = (const float*)d_in[5];
    float* out = (float*)d_out;

    char* ws = (char*)d_ws;
    float*  hxT0   = (float*) (ws);                 // 400*512*4 = 819200 each
    float*  hxT1   = (float*) (ws +  819200);
    float*  hyb0   = (float*) (ws + 1638400);
    float*  hyb1   = (float*) (ws + 2457600);
    double* expsum = (double*)(ws + 3276800);       // 512*16*8 = 65536
    double* tsum   = (double*)(ws + 3342336);       // 65536
    double* diagT  = (double*)(ws + 3407872);       // 4096

    void* args[] = { (void*)&X, (void*)&Y, (void*)&W1, (void*)&b1, (void*)&W2, (void*)&b2,
                     (void*)&hxT0, (void*)&hxT1, (void*)&hyb0, (void*)&hyb1,
                     (void*)&expsum, (void*)&tsum, (void*)&diagT, (void*)&out };
    hipLaunchCooperativeKernel((const void*)club_fused, dim3(256), dim3(1024),
                               args, 0, stream);
}

// Round 5
// 136.111 us; speedup vs baseline: 2.4841x; 2.4841x over previous
//
#include <hip/hip_runtime.h>
#include <math.h>

// CLUB_NCE: N=512, D=400, H=400.
// K1: hidden GEMMs. Per-lane operand via LDS, wave-uniform operand via scalar
//     loads (SGPR operand of v_fma). mat0: hxT[h][n] = X@W1x^T (lane=n);
//     mat1: hyb[n][h] = Y@W1y^T + b1 (lane=h). Both stores coalesced.
// K2: pair scores, zero LDS / zero barriers: B=hxT[h][j] streamed from L2
//     (lane=j), A=hyb[i][:] + W2 via uniform scalar loads. Fused softplus +
//     per-row fp64 wave reduction.
// K3: fp64 logsumexp assembly -> (lower, upper).

#define NSAMP 512
#define DIM 400
#define HID 400

// ---------------- K1 ----------------
// 216 blocks x 256 thr. Block = 64 lane-rows x 32 scalar-rows x 400 k.
// blocks 0..103:   mat0: bx = b%8 -> n-tile(64), by = b/8 (0..12) -> h-tile(32)
// blocks 104..215: mat1: bx = b'%16 -> n-tile(32 scalar), by = b'/16 (0..6) -> h-tile(64 lane)
__global__ __launch_bounds__(256) void club_gemm_kernel(
    const float* __restrict__ X, const float* __restrict__ Y,
    const float* __restrict__ W1, const float* __restrict__ b1,
    float* __restrict__ hxT, float* __restrict__ hyb)
{
    __shared__ __align__(16) float Ls[64 * 204];   // 52224 B, rows 16B-aligned
    const int t    = threadIdx.x;
    const int lane = t & 63;
    const int wave = __builtin_amdgcn_readfirstlane(t >> 6);
    const int b    = blockIdx.x;

    const float* __restrict__ Lbase;   // lane-dim matrix (staged in LDS)
    const float* __restrict__ Sbase;   // scalar-dim matrix (s_load path)
    int Lstride, Lcol0, Lrow0, Lrowmax;
    int Sstride, Scol0, Srow0, Srowmax;
    float* __restrict__ D;
    int Dstride, Dcol0;
    int mat;

    if (b < 104) {                      // mat0: hx^T
        mat = 0;
        const int bx = b & 7, by = b >> 3;          // by 0..12
        Lbase = X;  Lstride = DIM;     Lcol0 = 0;   Lrow0 = bx * 64; Lrowmax = NSAMP - 1;
        Sbase = W1; Sstride = 2 * DIM; Scol0 = 0;   Srow0 = by * 32; Srowmax = HID - 1;
        D = hxT; Dstride = NSAMP; Dcol0 = bx * 64;  // D[srow][n]
    } else {                            // mat1: hy + b1
        mat = 1;
        const int bb = b - 104;
        const int bx = bb & 15, by = bb >> 4;       // by 0..6
        Lbase = W1; Lstride = 2 * DIM; Lcol0 = DIM; Lrow0 = by * 64; Lrowmax = HID - 1;
        Sbase = Y;  Sstride = DIM;     Scol0 = 0;   Srow0 = bx * 32; Srowmax = NSAMP - 1;
        D = hyb; Dstride = HID; Dcol0 = by * 64;    // D[srow][h]
    }

    float acc[8];
#pragma unroll
    for (int c = 0; c < 8; c++) acc[c] = 0.f;

    const int srow_base = Srow0 + wave * 8;         // wave-uniform

    for (int kc = 0; kc < DIM; kc += 200) {
        __syncthreads();
        // stage L[Lrow0..+64)[kc..+200) -> Ls[row][k] stride 204, f4 coalesced reads
        for (int idx = t; idx < 3200; idx += 256) {
            int row = idx / 50, q = idx % 50;
            int r = Lrow0 + row; if (r > Lrowmax) r = Lrowmax;
            float4 v = *(const float4*)(Lbase + (size_t)r * Lstride + Lcol0 + kc + 4 * q);
            *(float4*)(Ls + row * 204 + 4 * q) = v;
        }
        __syncthreads();
#pragma unroll 2
        for (int k4 = 0; k4 < 50; k4++) {
            float4 xv = *(const float4*)(Ls + lane * 204 + 4 * k4);
#pragma unroll
            for (int c = 0; c < 8; c++) {
                int sr = srow_base + c; if (sr > Srowmax) sr = Srowmax;   // uniform
                float4 wv = *(const float4*)(Sbase + (size_t)sr * Sstride + Scol0 + kc + 4 * k4);
                acc[c] = fmaf(xv.x, wv.x, acc[c]);
                acc[c] = fmaf(xv.y, wv.y, acc[c]);
                acc[c] = fmaf(xv.z, wv.z, acc[c]);
                acc[c] = fmaf(xv.w, wv.w, acc[c]);
            }
        }
    }

    if (mat == 1) {
        int hl = Lrow0 + lane; if (hl > HID - 1) hl = HID - 1;
        float bv = b1[hl];
#pragma unroll
        for (int c = 0; c < 8; c++) acc[c] += bv;
        if (Lrow0 + lane < HID) {
#pragma unroll
            for (int c = 0; c < 8; c++) {
                int sr = srow_base + c;   // n rows, always < 512
                D[(size_t)sr * Dstride + Dcol0 + lane] = acc[c];
            }
        }
    } else {
#pragma unroll
        for (int c = 0; c < 8; c++) {
            int sr = srow_base + c;       // h rows, guard 400
            if (sr < HID)
                D[(size_t)sr * Dstride + Dcol0 + lane] = acc[c];
        }
    }
}

// ---------------- K2: pair scores, no LDS, no barriers ----------------
// grid (8 j-tiles, 32 i-tiles), block 256 (4 waves). lane = j, wave -> 4 i-rows.
__global__ __launch_bounds__(256) void club_pair_kernel(
    const float* __restrict__ hxT, const float* __restrict__ hyb,
    const float* __restrict__ W2, const float* __restrict__ b2,
    double* __restrict__ expsum, double* __restrict__ tsum,
    double* __restrict__ diagT)
{
    const int t    = threadIdx.x;
    const int lane = t & 63;
    const int wave = __builtin_amdgcn_readfirstlane(t >> 6);
    const int j0   = blockIdx.x * 64;
    const int j    = j0 + lane;
    const int i0   = blockIdx.y * 16 + wave * 4;    // uniform

    float acc[4] = {0.f, 0.f, 0.f, 0.f};

    const float* __restrict__ Bp = hxT + j;         // column j, stride 512

#pragma unroll 2
    for (int g = 0; g < 50; g++) {
        const int h = 8 * g;
        // per-lane B values: 8 independent b32 loads (L2-resident column reads)
        float bv[8];
#pragma unroll
        for (int u = 0; u < 8; u++)
            bv[u] = Bp[(size_t)(h + u) * NSAMP];
        // uniform W2 + A fragments -> scalar loads
        const float* __restrict__ wp = W2 + h;
#pragma unroll
        for (int r = 0; r < 4; r++) {
            const float* __restrict__ ap = hyb + (size_t)(i0 + r) * HID + h;  // uniform
            float a;
#pragma unroll
            for (int u = 0; u < 8; u++) {
                a = ap[u] + bv[u];
                acc[r] = fmaf(fmaxf(a, 0.f), wp[u], acc[r]);
            }
        }
    }

    // epilogue: softplus + fp64 reduction over the 64 j-lanes
    const float bb2 = b2[0];
#pragma unroll
    for (int r = 0; r < 4; r++) {
        const int i = i0 + r;
        float s  = acc[r] + bb2;
        float es = expf(s);
        float T  = log1pf(es);               // softplus
        if (j == i) diagT[i] = (double)T;    // T0[i]
        double eD = 1.0 + (double)es;        // exp(softplus(s)) exactly
        double tD = (double)T;
        for (int off = 32; off > 0; off >>= 1) {
            eD += __shfl_down(eD, off);
            tD += __shfl_down(tD, off);
        }
        if (lane == 0) {
            expsum[i * 8 + blockIdx.x] = eD;
            tsum  [i * 8 + blockIdx.x] = tD;
        }
    }
}

// ---------------- K3: final assembly ----------------
__global__ __launch_bounds__(512) void club_final_kernel(
    const double* __restrict__ expsum, const double* __restrict__ tsum,
    const double* __restrict__ diagT, float* __restrict__ out)
{
    __shared__ double sh[3 * 512];
    const int t = threadIdx.x;   // = i
    double es = 0.0, ts = 0.0;
#pragma unroll
    for (int b = 0; b < 8; b++) { es += expsum[t * 8 + b]; ts += tsum[t * 8 + b]; }
    sh[t] = log(es); sh[512 + t] = ts; sh[1024 + t] = diagT[t];
    __syncthreads();
    for (int off = 256; off > 0; off >>= 1) {
        if (t < off) {
            sh[t]        += sh[t + off];
            sh[512 + t]  += sh[512 + t + off];
            sh[1024 + t] += sh[1024 + t + off];
        }
        __syncthreads();
    }
    if (t == 0) {
        double t0m  = sh[1024] / 512.0;
        double lsem = sh[0]    / 512.0;
        double t1m  = sh[512]  / (512.0 * 512.0);
        out[0] = (float)(t0m - (lsem - log(512.0)));
        out[1] = (float)(t0m - t1m);
    }
}

extern "C" void kernel_launch(void* const* d_in, const int* in_sizes, int n_in,
                              void* d_out, int out_size, void* d_ws, size_t ws_size,
                              hipStream_t stream) {
    const float* X  = (const float*)d_in[0];
    const float* Y  = (const float*)d_in[1];
    const float* W1 = (const float*)d_in[2];
    const float* b1 = (const float*)d_in[3];
    const float* W2 = (const float*)d_in[4];
    const float* b2 = (const float*)d_in[5];
    float* out = (float*)d_out;

    char* ws = (char*)d_ws;
    float*  hxT    = (float*) (ws);                 // 400*512*4 = 819200
    float*  hyb    = (float*) (ws +  819200);       // 512*400*4 = 819200
    double* expsum = (double*)(ws + 1638400);       // 512*8*8   = 32768
    double* tsum   = (double*)(ws + 1671168);       // 32768
    double* diagT  = (double*)(ws + 1703936);       // 4096

    club_gemm_kernel <<<dim3(216),    256, 0, stream>>>(X, Y, W1, b1, hxT, hyb);
    club_pair_kernel <<<dim3(8, 32),  256, 0, stream>>>(hxT, hyb, W2, b2,
                                                        expsum, tsum, diagT);
    club_final_kernel<<<1, 512, 0, stream>>>(expsum, tsum, diagT, out);
}

// Round 6
// 110.053 us; speedup vs baseline: 3.0723x; 1.2368x over previous
//
#include <hip/hip_runtime.h>
#include <math.h>

// CLUB_NCE: N=512, D=400, H=400.
// K1  : hidden GEMM partials, k-split 2 across grid. 848 blocks -> 3.3 waves/SIMD.
//       lane-dim operand staged in LDS (one barrier), 4 wave-uniform scalar rows
//       per thread (s_load path). mat0 -> hxT_p[h][n], mat1 -> hyb_p[n][h] (+b1).
// K1.5: combine k-half partials -> hxT, hyb (pure streaming, 400 blocks).
// K2  : pair scores. 1024 blocks (4 waves/SIMD), thread = one (i,j) pair,
//       no LDS / no barriers: B = hxT[h][j] b32-coalesced from L2, A/W2 scalar.
//       Fused softplus + per-row fp64 wave reduction.
// K3  : fp64 logsumexp assembly -> (lower, upper).

#define NSAMP 512
#define DIM 400
#define HID 400

// ---------------- K1 ----------------
// blocks 0..399   : mat0: kh=b&1, bx=(b>>1)&7 -> n0=bx*64 (lane), by=b>>4 (0..24) -> h0=by*16
// blocks 400..847 : mat1: bb=b-400: kh=bb&1, bx=(bb>>1)&31 -> n0=bx*16, by=bb>>6 (0..6) -> h0=by*64 (lane)
__global__ __launch_bounds__(256) void club_gemm_kernel(
    const float* __restrict__ X, const float* __restrict__ Y,
    const float* __restrict__ W1, const float* __restrict__ b1,
    float* __restrict__ hxT0, float* __restrict__ hxT1,
    float* __restrict__ hyb0, float* __restrict__ hyb1)
{
    __shared__ __align__(16) float Ls[64 * 204];   // 52224 B -> 3 blocks/CU
    const int t    = threadIdx.x;
    const int lane = t & 63;
    const int wave = __builtin_amdgcn_readfirstlane(t >> 6);
    const int b    = blockIdx.x;

    const float* __restrict__ Lbase;   // lane-dim matrix (LDS-staged)
    const float* __restrict__ Sbase;   // scalar-dim matrix (s_load)
    int Lstride, Lcol0, Lrow0, Lrowmax, Sstride, Scol0, srow_base;
    int kh, mat;

    if (b < 400) {                    // mat0
        mat = 0; kh = b & 1;
        const int bx = (b >> 1) & 7, by = b >> 4;
        Lbase = X;  Lstride = DIM;     Lcol0 = 0;   Lrow0 = bx * 64; Lrowmax = NSAMP - 1;
        Sbase = W1; Sstride = 2 * DIM; Scol0 = 0;
        srow_base = by * 16 + wave * 4;             // h rows, max 384+12+3=399
    } else {                          // mat1
        mat = 1;
        const int bb = b - 400; kh = bb & 1;
        const int bx = (bb >> 1) & 31, by = bb >> 6;
        Lbase = W1; Lstride = 2 * DIM; Lcol0 = DIM; Lrow0 = by * 64; Lrowmax = HID - 1;
        Sbase = Y;  Sstride = DIM;     Scol0 = 0;
        srow_base = bx * 16 + wave * 4;             // n rows, max 496+15=511
    }
    const int kc0 = kh * 200;

    // stage lane-dim tile: 64 rows x 200 k -> Ls, coalesced float4
    for (int idx = t; idx < 3200; idx += 256) {
        int row = idx / 50, q = idx % 50;
        int r = Lrow0 + row; if (r > Lrowmax) r = Lrowmax;
        float4 v = *(const float4*)(Lbase + (size_t)r * Lstride + Lcol0 + kc0 + 4 * q);
        *(float4*)(Ls + row * 204 + 4 * q) = v;
    }
    __syncthreads();

    float acc[4] = {0.f, 0.f, 0.f, 0.f};
#pragma unroll 2
    for (int k4 = 0; k4 < 50; k4++) {
        float4 xv = *(const float4*)(Ls + lane * 204 + 4 * k4);
#pragma unroll
        for (int c = 0; c < 4; c++) {
            const float* __restrict__ wp =
                Sbase + (size_t)(srow_base + c) * Sstride + Scol0 + kc0 + 4 * k4;  // uniform
            float4 wv = *(const float4*)wp;
            acc[c] = fmaf(xv.x, wv.x, acc[c]);
            acc[c] = fmaf(xv.y, wv.y, acc[c]);
            acc[c] = fmaf(xv.z, wv.z, acc[c]);
            acc[c] = fmaf(xv.w, wv.w, acc[c]);
        }
    }

    if (mat == 0) {                   // store hxT_p[h][n], lane=n coalesced
        float* __restrict__ dst = kh ? hxT1 : hxT0;
#pragma unroll
        for (int c = 0; c < 4; c++)
            dst[(size_t)(srow_base + c) * NSAMP + Lrow0 + lane] = acc[c];
    } else {                          // store hyb_p[n][h], lane=h coalesced
        float* __restrict__ dst = kh ? hyb1 : hyb0;
        const int h = Lrow0 + lane;
        if (h < HID) {
            if (kh == 0) {
                float bv = b1[h];
#pragma unroll
                for (int c = 0; c < 4; c++) acc[c] += bv;
            }
#pragma unroll
            for (int c = 0; c < 4; c++)
                dst[(size_t)(srow_base + c) * HID + h] = acc[c];
        }
    }
}

// ---------------- K1.5: combine k-half partials ----------------
// 400 blocks x 256 thr; one float4 per thread. [0,51200) -> hxT, [51200,102400) -> hyb
__global__ __launch_bounds__(256) void club_combine_kernel(
    const float4* __restrict__ hxT0, const float4* __restrict__ hxT1,
    const float4* __restrict__ hyb0, const float4* __restrict__ hyb1,
    float4* __restrict__ hxT, float4* __restrict__ hyb)
{
    const int idx = blockIdx.x * 256 + threadIdx.x;
    if (idx < 51200) {
        float4 a = hxT0[idx], b = hxT1[idx];
        hxT[idx] = make_float4(a.x + b.x, a.y + b.y, a.z + b.z, a.w + b.w);
    } else {
        const int k = idx - 51200;
        float4 a = hyb0[k], b = hyb1[k];
        hyb[k] = make_float4(a.x + b.x, a.y + b.y, a.z + b.z, a.w + b.w);
    }
}

// ---------------- K2: pair scores, no LDS, no barriers ----------------
// grid (8 jx, 128 iy) = 1024 blocks, 256 thr. lane=j, wave=i (4 i per block).
__global__ __launch_bounds__(256) void club_pair_kernel(
    const float* __restrict__ hxT, const float* __restrict__ hyb,
    const float* __restrict__ W2, const float* __restrict__ b2,
    double* __restrict__ expsum, double* __restrict__ tsum,
    double* __restrict__ diagT)
{
    const int t    = threadIdx.x;
    const int lane = t & 63;
    const int wave = __builtin_amdgcn_readfirstlane(t >> 6);
    const int jx   = blockIdx.x;
    const int j    = jx * 64 + lane;
    const int i    = blockIdx.y * 4 + wave;     // uniform

    const float* __restrict__ Bp = hxT + j;     // column j, stride NSAMP
    const float* __restrict__ Ap = hyb + (size_t)i * HID;

    float acc0 = 0.f, acc1 = 0.f;
#pragma unroll 2
    for (int g = 0; g < 50; g++) {
        const int h = 8 * g;
        float bv[8];
#pragma unroll
        for (int u = 0; u < 8; u++)
            bv[u] = Bp[(size_t)(h + u) * NSAMP];        // b32 coalesced, L2-hit
        float4 a0 = *(const float4*)(Ap + h);           // uniform -> s_load
        float4 a1 = *(const float4*)(Ap + h + 4);
        float4 w0 = *(const float4*)(W2 + h);
        float4 w1 = *(const float4*)(W2 + h + 4);
        acc0 = fmaf(fmaxf(a0.x + bv[0], 0.f), w0.x, acc0);
        acc1 = fmaf(fmaxf(a0.y + bv[1], 0.f), w0.y, acc1);
        acc0 = fmaf(fmaxf(a0.z + bv[2], 0.f), w0.z, acc0);
        acc1 = fmaf(fmaxf(a0.w + bv[3], 0.f), w0.w, acc1);
        acc0 = fmaf(fmaxf(a1.x + bv[4], 0.f), w1.x, acc0);
        acc1 = fmaf(fmaxf(a1.y + bv[5], 0.f), w1.y, acc1);
        acc0 = fmaf(fmaxf(a1.z + bv[6], 0.f), w1.z, acc0);
        acc1 = fmaf(fmaxf(a1.w + bv[7], 0.f), w1.w, acc1);
    }

    // epilogue: softplus + fp64 reduction over the 64 j-lanes
    float s  = (acc0 + acc1) + b2[0];
    float es = expf(s);
    float T  = log1pf(es);               // softplus
    if (j == i) diagT[i] = (double)T;    // T0[i]
    double eD = 1.0 + (double)es;        // exp(softplus(s)) exactly
    double tD = (double)T;
    for (int off = 32; off > 0; off >>= 1) {
        eD += __shfl_down(eD, off);
        tD += __shfl_down(tD, off);
    }
    if (lane == 0) {
        expsum[i * 8 + jx] = eD;
        tsum  [i * 8 + jx] = tD;
    }
}

// ---------------- K3: final assembly ----------------
__global__ __launch_bounds__(512) void club_final_kernel(
    const double* __restrict__ expsum, const double* __restrict__ tsum,
    const double* __restrict__ diagT, float* __restrict__ out)
{
    __shared__ double sh[3 * 512];
    const int t = threadIdx.x;   // = i
    double es = 0.0, ts = 0.0;
#pragma unroll
    for (int b = 0; b < 8; b++) { es += expsum[t * 8 + b]; ts += tsum[t * 8 + b]; }
    sh[t] = log(es); sh[512 + t] = ts; sh[1024 + t] = diagT[t];
    __syncthreads();
    for (int off = 256; off > 0; off >>= 1) {
        if (t < off) {
            sh[t]        += sh[t + off];
            sh[512 + t]  += sh[512 + t + off];
            sh[1024 + t] += sh[1024 + t + off];
        }
        __syncthreads();
    }
    if (t == 0) {
        double t0m  = sh[1024] / 512.0;
        double lsem = sh[0]    / 512.0;
        double t1m  = sh[512]  / (512.0 * 512.0);
        out[0] = (float)(t0m - (lsem - log(512.0)));
        out[1] = (float)(t0m - t1m);
    }
}

extern "C" void kernel_launch(void* const* d_in, const int* in_sizes, int n_in,
                              void* d_out, int out_size, void* d_ws, size_t ws_size,
                              hipStream_t stream) {
    const float* X  = (const float*)d_in[0];
    const float* Y  = (const float*)d_in[1];
    const float* W1 = (const float*)d_in[2];
    const float* b1 = (const float*)d_in[3];
    const float* W2 = (const float*)d_in[4];
    const float* b2 = (const float*)d_in[5];
    float* out = (float*)d_out;

    char* ws = (char*)d_ws;                         // 819200 B each matrix buffer
    float*  hxT0   = (float*) (ws);
    float*  hxT1   = (float*) (ws +  819200);
    float*  hyb0   = (float*) (ws + 1638400);
    float*  hyb1   = (float*) (ws + 2457600);
    float*  hxT    = (float*) (ws + 3276800);
    float*  hyb    = (float*) (ws + 4096000);
    double* expsum = (double*)(ws + 4915200);       // 512*8*8 = 32768
    double* tsum   = (double*)(ws + 4947968);       // 32768
    double* diagT  = (double*)(ws + 4980736);       // 4096  -> ~4.98 MB total

    club_gemm_kernel   <<<dim3(848),    256, 0, stream>>>(X, Y, W1, b1,
                                                          hxT0, hxT1, hyb0, hyb1);
    club_combine_kernel<<<dim3(400),    256, 0, stream>>>((const float4*)hxT0, (const float4*)hxT1,
                                                          (const float4*)hyb0, (const float4*)hyb1,
                                                          (float4*)hxT, (float4*)hyb);
    club_pair_kernel   <<<dim3(8, 128), 256, 0, stream>>>(hxT, hyb, W2, b2,
                                                          expsum, tsum, diagT);
    club_final_kernel  <<<1, 512, 0, stream>>>(expsum, tsum, diagT, out);
}